// Round 1
// baseline (257.428 us; speedup 1.0000x reference)
//
#include <hip/hip_runtime.h>
#include <math.h>

// OrientationFilter: batched 2-state Kalman filter (theta, omega) with angle wrap.
// Inputs (setup_inputs order):
//   d_in[0] x0      [B,2,1] f32
//   d_in[1] P0      [B,2,2] f32
//   d_in[2] delta_t [B]     f32
//   d_in[3] Q       [B,2,2] f32 (diagonal)
//   d_in[4] z       [B,1,1] f32
//   d_in[5] R       [B,1,1] f32
// Output: x [B,2,1] then P [B,2,2], concatenated flat (6*B floats).

#define TWO_PI_F 6.28318530717958647692f
#define INV_TWO_PI_F 0.15915494309189533577f

__device__ __forceinline__ float wrap_to_pi(float a) {
    // a - 2*pi*round(a / 2*pi); rintf = round-to-nearest-even, matches jnp.round
    return fmaf(-TWO_PI_F, rintf(a * INV_TWO_PI_F), a);
}

__global__ void __launch_bounds__(256) orientation_filter_kernel(
    const float* __restrict__ x0,
    const float* __restrict__ P0,
    const float* __restrict__ dt_in,
    const float* __restrict__ Q,
    const float* __restrict__ z_in,
    const float* __restrict__ R_in,
    float* __restrict__ out_x,   // [B,2]
    float* __restrict__ out_P,   // [B,2,2]
    int B)
{
    int stride = gridDim.x * blockDim.x;
    for (int b = blockIdx.x * blockDim.x + threadIdx.x; b < B; b += stride) {
        // ---- loads (vectorized, coalesced) ----
        float2 x  = *reinterpret_cast<const float2*>(x0 + 2 * b);
        float4 p  = *reinterpret_cast<const float4*>(P0 + 4 * b);   // p00 p01 p10 p11
        float  dt = dt_in[b];
        float4 q  = *reinterpret_cast<const float4*>(Q  + 4 * b);   // q0 0 0 q1
        float  z  = z_in[b];
        float  R  = R_in[b];

        // ---- predict ----
        // x = F x0, F = [[1,dt],[0,1]]
        float theta = wrap_to_pi(fmaf(dt, x.y, x.x));
        float omega = x.y;
        // P = F P0 F^T + Q
        float fp00 = fmaf(dt, p.z, p.x);   // p00 + dt*p10
        float fp01 = fmaf(dt, p.w, p.y);   // p01 + dt*p11
        float P00 = fmaf(dt, fp01, fp00) + q.x;
        float P01 = fp01;
        float P10 = fmaf(dt, p.w, p.z);    // p10 + dt*p11
        float P11 = p.w + q.w;

        // ---- update ----  H = [1,0]
        float S    = P00 + R;
        float invS = __frcp_rn(S);         // IEEE-correct reciprocal
        float K0   = P00 * invS;
        float K1   = P10 * invS;
        float innov = wrap_to_pi(z - theta);
        float xn0 = wrap_to_pi(fmaf(K0, innov, theta));
        float xn1 = fmaf(K1, innov, omega);
        // P = (I - K H) P  ;  I-KH = [[1-K0, 0], [-K1, 1]]
        float omK0 = 1.0f - K0;
        float Pn00 = omK0 * P00;
        float Pn01 = omK0 * P01;
        float Pn10 = fmaf(-K1, P00, P10);
        float Pn11 = fmaf(-K1, P01, P11);

        // ---- stores (vectorized) ----
        *reinterpret_cast<float2*>(out_x + 2 * b) = make_float2(xn0, xn1);
        *reinterpret_cast<float4*>(out_P + 4 * b) = make_float4(Pn00, Pn01, Pn10, Pn11);
    }
}

extern "C" void kernel_launch(void* const* d_in, const int* in_sizes, int n_in,
                              void* d_out, int out_size, void* d_ws, size_t ws_size,
                              hipStream_t stream) {
    const float* x0 = (const float*)d_in[0];
    const float* P0 = (const float*)d_in[1];
    const float* dt = (const float*)d_in[2];
    const float* Q  = (const float*)d_in[3];
    const float* z  = (const float*)d_in[4];
    const float* R  = (const float*)d_in[5];

    int B = in_sizes[2];                 // delta_t is [B]
    float* out_x = (float*)d_out;        // first 2*B floats
    float* out_P = out_x + (size_t)2 * B; // next 4*B floats (16B-aligned: 2*B*4 bytes)

    const int block = 256;
    int grid = (B + block - 1) / block;
    const int max_grid = 256 * 8;        // memory-bound: cap and grid-stride
    if (grid > max_grid) grid = max_grid;

    orientation_filter_kernel<<<grid, block, 0, stream>>>(
        x0, P0, dt, Q, z, R, out_x, out_P, B);
}